// Round 15
// baseline (3134.234 us; speedup 1.0000x reference)
//
#include <hip/hip_runtime.h>

// Multi-layer tanh RNN — R15: wave-private pipelines, correctly resourced.
// R14's failure causes fixed: (1) VGPR 252 (Bf[8][7]=224) strangled the wave
// -> now only h-half weights in regs (Bf[4][7]=112), inp-half weights in
// block-shared LDS (8 waves = same layer, loaded once); (2) 320 1-wave blocks
// spread thin -> now 40 blocks x 512 thr (8 wave-private pipelines each):
// 1 block/CU on 40 CUs, 2 waves/SIMD, zero per-step barriers.
// bf16 everywhere off the accumulator: h state in LDS bf16, ring bf16 ->
// per-step build1 VALU gone (A operands load ready-to-MFMA). Matmul input
// precision unchanged vs R13/R14 (RTN bf16; R14 absmax 2.38e-3 proves it).
// Flag protocol per wave = R8/R14 exact (agent scope, K=16/RD=32).

#define HH   100   // hidden
#define NL   10    // layers
#define BBS  512   // batch
#define TTS  512   // time
#define NB   32    // batch chunks (16 rows each)
#define NT   512   // threads per block = 8 waves = 8 pipelines
#define NTL  7     // column tiles (7*16 = 112 >= 100)
#define HSS  136   // LDS short stride (272B: 16B-aligned, conflict-spread)
#define RSS  128   // ring short stride per row
#define SLOTS (16 * RSS)   // ring slot shorts = 2048 (4096 B)

typedef __attribute__((ext_vector_type(8))) short short8;
typedef __attribute__((ext_vector_type(4))) float f32x4;

__global__ void init_ws_kernel(int* wsi) {
  int i = blockIdx.x * blockDim.x + threadIdx.x;
  if (i < 16384) wsi[i] = 0;   // zero both flag regions (64KB)
}

__device__ __forceinline__ int flag_idx(int iface, int chunk) {
  return (iface * NB + chunk) * 16;
}

__device__ __forceinline__ float fast_tanh(float v) {
  float e = __expf(2.0f * v);
  return 1.0f - 2.0f * __builtin_amdgcn_rcpf(e + 1.0f);
}

__device__ __forceinline__ unsigned short bf_rtn(float x) {
  return (unsigned short)((__float_as_uint(x) + 0x8000u) >> 16);
}

__device__ __forceinline__ unsigned pack_rtn(float x0, float x1) {
  unsigned u0 = __float_as_uint(x0) + 0x8000u;
  unsigned u1 = __float_as_uint(x1) + 0x8000u;
  return (u0 >> 16) | (u1 & 0xFFFF0000u);
}

__device__ __forceinline__ short8 build1(f32x4 lo, f32x4 hi) {
  __attribute__((ext_vector_type(4))) unsigned int w;
  w[0] = pack_rtn(lo[0], lo[1]);
  w[1] = pack_rtn(lo[2], lo[3]);
  w[2] = pack_rtn(hi[0], hi[1]);
  w[3] = pack_rtn(hi[2], hi[3]);
  return __builtin_bit_cast(short8, w);
}

__global__ __launch_bounds__(NT, 2) void rnn_pipe(
    const float* __restrict__ x,     // [B,T,1]
    const float* __restrict__ h0,    // [L,B,H]
    const float* __restrict__ Wih0,  // [H,1]
    const float* __restrict__ Wih,   // [L-1,H,H]
    const float* __restrict__ Whh,   // [L,H,H]
    const float* __restrict__ bih,   // [L,H]
    const float* __restrict__ bhh,   // [L,H]
    const float* __restrict__ Wout,  // [1,H]
    const float* __restrict__ bout,  // [1]
    float* __restrict__ out,         // [B*T] outs ++ [L*B*H] h_final
    unsigned short* __restrict__ ring,
    int*   __restrict__ wsi,
    int Kv, int RDv)
{
  const int layer = blockIdx.x >> 2;        // 40 blocks: layer*4 + cg
  const int cg    = blockIdx.x & 3;
  const int tid   = threadIdx.x;
  const int wave  = tid >> 6, lane = tid & 63;
  const int quad  = lane >> 4, lp = lane & 15;
  const int chunk = cg * 8 + wave;          // this wave's 16 batch rows
  const int Km = Kv - 1, RDm = RDv - 1;

  // LDS: hb 8*2*16*136*2 = 69.6KB (per-wave h state, bf16, double-buffered)
  //      Bw 112*136*2    = 30.5KB (block-shared inp-half weights, bf16)
  __shared__ unsigned short hb[8][2][16][HSS];
  __shared__ unsigned short Bw[112][HSS];

  // ---- init: own-wave h region; block-shared Bw (one __syncthreads total) --
  for (int i = lane; i < 2 * 16 * HSS; i += 64)
    (&hb[wave][0][0][0])[i] = 0;
  for (int idx = lane; idx < 16 * HH; idx += 64) {
    const int row = idx / HH, col = idx % HH;
    hb[wave][0][row][col] =
        bf_rtn(h0[((size_t)layer * BBS + chunk * 16 + row) * HH + col]);
  }
  for (int i = tid; i < 112 * HSS; i += NT) {
    const int n = i / HSS, k = i % HSS;
    float w = 0.f;
    if (layer > 0 && n < HH && k < HH)
      w = Wih[(size_t)(layer - 1) * HH * HH + n * HH + k];
    Bw[n][k] = bf_rtn(w);
  }
  __syncthreads();   // Bw visible to all waves (only barrier in the kernel)

  // ---- per-lane constants (col = ntl*16 + lp) ----
  float br[NTL], w0r[NTL], wo[NTL];
  #pragma unroll
  for (int ntl = 0; ntl < NTL; ++ntl) {
    const int col = ntl * 16 + lp;
    br[ntl]  = (col < HH) ? (bih[layer * HH + col] + bhh[layer * HH + col]) : 0.f;
    w0r[ntl] = (col < HH) ? Wih0[col] : 0.f;
    wo[ntl]  = (col < HH) ? Wout[col] : 0.f;
  }
  const float boutv = bout[0];

  // ---- reg-resident h-half weights (Whh), single-plane bf16: 112 VGPRs ----
  short8 Bf[4][NTL];
  #pragma unroll
  for (int kc = 0; kc < 4; ++kc) {
    #pragma unroll
    for (int ntl = 0; ntl < NTL; ++ntl) {
      const int n = ntl * 16 + lp;
      f32x4 wlo = {}, whi = {};
      #pragma unroll
      for (int j = 0; j < 8; ++j) {
        const int k = kc * 32 + quad * 8 + j;
        float w = 0.f;
        if (k < HH && n < HH) w = Whh[(size_t)layer * HH * HH + n * HH + k];
        if (j < 4) wlo[j] = w; else whi[j - 4] = w;
      }
      Bf[kc][ntl] = build1(wlo, whi);
    }
  }

  // ---- flags / ring (per-wave, R8/R14-proven protocol, agent scope) ----
  int* prog_in  = (layer > 0)      ? wsi + flag_idx(layer - 1, chunk)        : nullptr;
  int* cons_in  = (layer > 0)      ? wsi + 8192 + flag_idx(layer - 1, chunk) : nullptr;
  int* prog_out = (layer < NL - 1) ? wsi + flag_idx(layer, chunk)            : nullptr;
  int* cons_out = (layer < NL - 1) ? wsi + 8192 + flag_idx(layer, chunk)     : nullptr;
  const unsigned short* ring_in = (layer > 0)
      ? ring + (size_t)((layer - 1) * NB + chunk) * RDv * SLOTS : nullptr;
  unsigned short* ring_out = (layer < NL - 1)
      ? ring + (size_t)(layer * NB + chunk) * RDv * SLOTS : nullptr;

  short8 a_cur[4], a_nxt[4];   // inp A-fragments (bf16, ready for MFMA)
  bool have_next = false;
  float xr[4] = {}, px[4] = {};
  if (layer == 0) {
    #pragma unroll
    for (int r = 0; r < 4; ++r)
      xr[r] = x[(size_t)(chunk * 16 + quad * 4 + r) * TTS];
  }

  for (int t = 0; t < TTS; ++t) {
    const int par = t & 1, nxt = par ^ 1;
    const bool batch_start = (t & Km) == 0;
    const bool batch_last  = (t & Km) == Km;

    // ---- batch boundary: spin (wave-uniform), acquire, load slot t ----
    if (batch_start) {
      if (layer > 0) {
        while (__hip_atomic_load(prog_in, __ATOMIC_RELAXED, __HIP_MEMORY_SCOPE_AGENT) < t + Kv)
          __builtin_amdgcn_s_sleep(1);
        (void)__hip_atomic_load(prog_in, __ATOMIC_ACQUIRE, __HIP_MEMORY_SCOPE_AGENT);
        const unsigned short* src = ring_in + (size_t)(t & RDm) * SLOTS + lp * RSS;
        #pragma unroll
        for (int kc = 0; kc < 4; ++kc)
          a_cur[kc] = *(const short8*)(src + kc * 32 + quad * 8);
      }
      if (layer < NL - 1 && t + Kv > RDv) {
        while (__hip_atomic_load(cons_out, __ATOMIC_RELAXED, __HIP_MEMORY_SCOPE_AGENT) < t + Kv - RDv)
          __builtin_amdgcn_s_sleep(1);
      }
    } else if (have_next) {
      #pragma unroll
      for (int kc = 0; kc < 4; ++kc) a_cur[kc] = a_nxt[kc];
    }
    have_next = false;

    // ---- prefetch inp/x for t+1 ----
    if (layer > 0) {
      if (!batch_last && t + 1 < TTS) {
        const unsigned short* src = ring_in + (size_t)((t + 1) & RDm) * SLOTS + lp * RSS;
        #pragma unroll
        for (int kc = 0; kc < 4; ++kc)
          a_nxt[kc] = *(const short8*)(src + kc * 32 + quad * 8);
        have_next = true;
      }
    } else if (t + 1 < TTS) {
      #pragma unroll
      for (int r = 0; r < 4; ++r)
        px[r] = x[(size_t)(chunk * 16 + quad * 4 + r) * TTS + (t + 1)];
    }

    // ---- MFMA: 7 independent chains; h from LDS (bf16, no conversion) ----
    f32x4 acc[NTL] = {};
    #pragma unroll
    for (int kc = 0; kc < 4; ++kc) {
      short8 A = *(const short8*)&hb[wave][par][lp][kc * 32 + quad * 8];
      #pragma unroll
      for (int ntl = 0; ntl < NTL; ++ntl)
        acc[ntl] = __builtin_amdgcn_mfma_f32_16x16x32_bf16(A, Bf[kc][ntl], acc[ntl], 0, 0, 0);
    }
    if (layer > 0) {
      #pragma unroll
      for (int kc = 0; kc < 4; ++kc) {
        #pragma unroll
        for (int ntl = 0; ntl < NTL; ++ntl) {
          short8 Bfrag = *(const short8*)&Bw[ntl * 16 + lp][kc * 32 + quad * 8];
          acc[ntl] = __builtin_amdgcn_mfma_f32_16x16x32_bf16(a_cur[kc], Bfrag, acc[ntl], 0, 0, 0);
        }
      }
    }

    // ---- epilogue: bias(+x*w0), tanh, bf16 pack, h/ring/out stores ----
    unsigned short* rdst = (layer < NL - 1)
        ? ring_out + (size_t)(t & RDm) * SLOTS : nullptr;
    #pragma unroll
    for (int r = 0; r < 4; ++r) {
      const int row = quad * 4 + r;
      float s9 = 0.f;
      #pragma unroll
      for (int ntl = 0; ntl < NTL; ++ntl) {
        float v = acc[ntl][r] + br[ntl];
        if (layer == 0) v += xr[r] * w0r[ntl];
        float h = fast_tanh(v);
        const int col = ntl * 16 + lp;
        unsigned short q = bf_rtn(h);
        hb[wave][nxt][row][col] = q;            // cols>=112 stay 0 forever
        if (layer < NL - 1) rdst[row * RSS + col] = q;
        if (t == TTS - 1 && col < HH)
          out[(size_t)BBS * TTS +
              ((size_t)layer * BBS + chunk * 16 + row) * HH + col] = h;
        if (layer == NL - 1) s9 += h * wo[ntl];
      }
      if (layer == NL - 1) {
        s9 += __shfl_xor(s9, 1, 16);
        s9 += __shfl_xor(s9, 2, 16);
        s9 += __shfl_xor(s9, 4, 16);
        s9 += __shfl_xor(s9, 8, 16);
        if (lp == 0)
          out[(size_t)(chunk * 16 + row) * TTS + t] = s9 + boutv;
      }
    }

    if (layer == 0 && t + 1 < TTS) {
      #pragma unroll
      for (int r = 0; r < 4; ++r) xr[r] = px[r];
    }

    // ---- flags (once per batch); wave-level RELEASE covers wave's stores --
    if (batch_last && lane == 0) {
      if (layer < NL - 1)
        __hip_atomic_store(prog_out, t + 1, __ATOMIC_RELEASE, __HIP_MEMORY_SCOPE_AGENT);
      if (layer > 0)
        __hip_atomic_store(cons_in, t + 1, __ATOMIC_RELAXED, __HIP_MEMORY_SCOPE_AGENT);
    }
  }
}

extern "C" void kernel_launch(void* const* d_in, const int* in_sizes, int n_in,
                              void* d_out, int out_size, void* d_ws, size_t ws_size,
                              hipStream_t stream) {
  const float* x    = (const float*)d_in[0];
  const float* h0   = (const float*)d_in[1];
  const float* Wih0 = (const float*)d_in[2];
  const float* Wih  = (const float*)d_in[3];
  const float* Whh  = (const float*)d_in[4];
  const float* bih  = (const float*)d_in[5];
  const float* bhh  = (const float*)d_in[6];
  const float* Wout = (const float*)d_in[7];
  const float* bout = (const float*)d_in[8];
  float* out = (float*)d_out;

  int* wsi = (int*)d_ws;
  unsigned short* ring = (unsigned short*)((char*)d_ws + 65536);

  // ring bytes = 9*32 * RD * 4096
  const size_t slot_bytes = (size_t)SLOTS * 2;   // 4096
  int RDv = 32;
  while (RDv > 2 && 65536 + (size_t)(NL - 1) * NB * RDv * slot_bytes > ws_size)
    RDv >>= 1;
  int Kv = RDv / 2;

  hipLaunchKernelGGL(init_ws_kernel, dim3(64), dim3(256), 0, stream, wsi);
  hipLaunchKernelGGL(rnn_pipe, dim3(NL * 4), dim3(NT), 0, stream,
                     x, h0, Wih0, Wih, Whh, bih, bhh, Wout, bout, out, ring, wsi,
                     Kv, RDv);
}

// Round 16
// 1370.790 us; speedup vs baseline: 2.2864x; 2.2864x over previous
//
#include <hip/hip_runtime.h>

// Multi-layer tanh RNN, layer-pipelined persistent kernel.
// R16 = R13 (best, 1519us) + bf16 LDS state (the last VALU-diet step):
//  - hbuf/ibuf hold RTN-bf16 activations; MFMA A-operand is a direct
//    ds_read_b128 (zero conversion; A-reads halve). Kills build1's ~96
//    VALU instr/thread/step; epilogue pack adds ~16.
//  - ring stays fp32 (R10 lesson: scattered b16 global stores poison vmcnt);
//    staging packs fp32->bf16 on the LDS write (amortized, tiny).
//  - matmul input precision unchanged (RTN bf16 as before); h_final written
//    fp32-exact from registers at t=TTS-1; layer-9 dot reconstructs h<<16.
// R14/R15 lesson: wave-private/no-barrier serializes the step 4x - the
// 4-wave column-split + 2 light barriers (R13) is the right shape.
// NB=32/BC=16, 2 blk/CU, agent flags, K=16/RD=32, deferred stores.

#define HH   100   // hidden
#define HS   132   // padded fp32 stride (bias etc.)
#define HSS  136   // bf16 LDS row stride in shorts (272B = 17*16, b128-aligned)
#define NL   10    // layers
#define BBS  512   // batch
#define TTS  512   // time
#define NB   32    // batch chunks
#define BC   16    // batch per chunk
#define NT   256   // threads per block

typedef __attribute__((ext_vector_type(8))) short short8;
typedef __attribute__((ext_vector_type(4))) float f32x4;
typedef __attribute__((ext_vector_type(2))) unsigned int u32x2;

__global__ void init_ws_kernel(int* wsi) {
  int i = blockIdx.x * blockDim.x + threadIdx.x;
  if (i < 16384) wsi[i] = 0;   // zero both flag regions (64KB)
}

__device__ __forceinline__ int flag_idx(int iface, int chunk) {
  return (iface * NB + chunk) * 16;
}

__device__ __forceinline__ void lds_barrier() {
  __asm__ __volatile__("s_waitcnt lgkmcnt(0)\n\ts_barrier" ::: "memory");
}
__device__ __forceinline__ void ctl_barrier() {
  __asm__ __volatile__("s_barrier" ::: "memory");
}

__device__ __forceinline__ float fast_tanh(float v) {
  float e = __expf(2.0f * v);
  return 1.0f - 2.0f * __builtin_amdgcn_rcpf(e + 1.0f);
}

__device__ __forceinline__ unsigned short bf_rtn(float x) {
  return (unsigned short)((__float_as_uint(x) + 0x8000u) >> 16);
}
__device__ __forceinline__ unsigned pack_rtn(float x0, float x1) {
  unsigned u0 = __float_as_uint(x0) + 0x8000u;
  unsigned u1 = __float_as_uint(x1) + 0x8000u;
  return (u0 >> 16) | (u1 & 0xFFFF0000u);
}
// f32x4 -> 4 bf16 packed in 8 bytes
__device__ __forceinline__ u32x2 pack4(f32x4 q) {
  u32x2 d;
  d[0] = pack_rtn(q[0], q[1]);
  d[1] = pack_rtn(q[2], q[3]);
  return d;
}

__global__ __launch_bounds__(NT, 2) void rnn_pipe(
    const float* __restrict__ x,     // [B,T,1]
    const float* __restrict__ h0,    // [L,B,H]
    const float* __restrict__ Wih0,  // [H,1]
    const float* __restrict__ Wih,   // [L-1,H,H]
    const float* __restrict__ Whh,   // [L,H,H]
    const float* __restrict__ bih,   // [L,H]
    const float* __restrict__ bhh,   // [L,H]
    const float* __restrict__ Wout,  // [1,H]
    const float* __restrict__ bout,  // [1]
    float* __restrict__ out,         // [B*T] outs ++ [L*B*H] h_final
    float* __restrict__ ring,
    int*   __restrict__ wsi,
    int Kv, int RDv)
{
  const int layer = blockIdx.x / NB;
  const int chunk = blockIdx.x % NB;
  const int tid   = threadIdx.x;
  const int Km = Kv - 1, RDm = RDv - 1;
  const int NE = BC * HH;  // 1600 elements per activation slot

  const int wave = tid >> 6, lane = tid & 63;
  const int quad = lane >> 4, lp = lane & 15;

  // LDS: 4*16*136*2 = 17.4KB state + ~1.7KB consts
  __shared__ unsigned short hbuf[2][BC][HSS];  // recurrent state bf16
  __shared__ unsigned short ibuf[2][BC][HSS];  // staged prev-layer input bf16
  __shared__ float bias[HS];
  __shared__ float wi0s[HS];
  __shared__ float wouts[HS];
  __shared__ float xin[2][BC];

  // ---- one-time LDS init ----
  for (int i = tid; i < 2 * BC * HSS; i += NT) {
    (&hbuf[0][0][0])[i] = 0; (&ibuf[0][0][0])[i] = 0;
  }
  for (int i = tid; i < HS; i += NT) {
    bias[i]  = (i < HH) ? (bih[layer * HH + i] + bhh[layer * HH + i]) : 0.f;
    wi0s[i]  = (i < HH) ? Wih0[i] : 0.f;
    wouts[i] = (i < HH) ? Wout[i] : 0.f;
  }
  if (tid < BC) { xin[0][tid] = 0.f; xin[1][tid] = 0.f; }
  __syncthreads();
  for (int idx = tid; idx < NE; idx += NT)
    hbuf[0][idx / HH][idx % HH] =
        bf_rtn(h0[((size_t)layer * BBS + chunk * BC + idx / HH) * HH + idx % HH]);
  __syncthreads();

  // ---- B-fragments in registers: fused W = [Whh (k 0..99) ; Wih (k 128..227)]
  // 2-plane (weight precision kept), 128 VGPRs.
  short8 Bf[8][2][2];
  #pragma unroll
  for (int kc = 0; kc < 8; ++kc) {
    #pragma unroll
    for (int ntl = 0; ntl < 2; ++ntl) {
      const int n = wave * 32 + ntl * 16 + lp;
      float wv[8];
      #pragma unroll
      for (int j = 0; j < 8; ++j) {
        const int k = kc * 32 + quad * 8 + j;
        float w = 0.f;
        if (kc < 4) {
          if (k < HH && n < HH) w = Whh[(size_t)layer * HH * HH + n * HH + k];
        } else {
          const int kk = k - 128;
          if (layer > 0 && kk >= 0 && kk < HH && n < HH)
            w = Wih[(size_t)(layer - 1) * HH * HH + n * HH + kk];
        }
        wv[j] = w;
      }
      // plane1 = truncate, plane2 = residual (exact split)
      __attribute__((ext_vector_type(4))) unsigned int p1, p2;
      #pragma unroll
      for (int j2 = 0; j2 < 4; ++j2) {
        unsigned ua = __float_as_uint(wv[2 * j2]), ub = __float_as_uint(wv[2 * j2 + 1]);
        p1[j2] = (ua >> 16) | (ub & 0xFFFF0000u);
        float ra = wv[2 * j2]     - __uint_as_float(ua & 0xFFFF0000u);
        float rb = wv[2 * j2 + 1] - __uint_as_float(ub & 0xFFFF0000u);
        p2[j2] = (__float_as_uint(ra) >> 16) | (__float_as_uint(rb) & 0xFFFF0000u);
      }
      Bf[kc][ntl][0] = __builtin_bit_cast(short8, p1);
      Bf[kc][ntl][1] = __builtin_bit_cast(short8, p2);
    }
  }

  // ---- flags / ring pointers (R8-proven protocol, agent scope) ----
  int* prog_in  = (layer > 0)      ? wsi + flag_idx(layer - 1, chunk)        : nullptr;
  int* cons_in  = (layer > 0)      ? wsi + 8192 + flag_idx(layer - 1, chunk) : nullptr;
  int* prog_out = (layer < NL - 1) ? wsi + flag_idx(layer, chunk)            : nullptr;
  int* cons_out = (layer < NL - 1) ? wsi + 8192 + flag_idx(layer, chunk)     : nullptr;
  const size_t slot_sz = (size_t)NE;  // 1600 floats
  float* ring_in  = (layer > 0)      ? ring + (size_t)((layer - 1) * NB + chunk) * RDv * slot_sz : nullptr;
  float* ring_out = (layer < NL - 1) ? ring + (size_t)(layer * NB + chunk) * RDv * slot_sz       : nullptr;

  const int jcv[2] = { wave * 32 + lp, wave * 32 + 16 + lp };   // C columns
  const float br[2]  = { bias[jcv[0]], bias[jcv[1]] };
  const float w0r[2] = { wi0s[jcv[0]], wi0s[jcv[1]] };
  const float boutv = bout[0];

  f32x4 hreg[2];             // step-t h values fp32 (deferred ring stores)
  float dso = 0.f;           // deferred layer-9 output
  float px = 0.f;
  bool have_ring_def = false, have_out_def = false;

  for (int t = 0; t < TTS; ++t) {
    const int par = t & 1, nxt = par ^ 1;
    const bool batch_start = (t & Km) == 0;
    const bool batch_last  = (t & Km) == Km;

    // ---- batch boundary: wait + exposed staging of slot t into parity par ----
    if (batch_start) {
      if (tid == 0) {
        if (layer > 0) {
          while (__hip_atomic_load(prog_in, __ATOMIC_RELAXED, __HIP_MEMORY_SCOPE_AGENT) < t + Kv)
            __builtin_amdgcn_s_sleep(1);
          (void)__hip_atomic_load(prog_in, __ATOMIC_ACQUIRE, __HIP_MEMORY_SCOPE_AGENT);
        }
        if (layer < NL - 1 && t + Kv > RDv) {
          while (__hip_atomic_load(cons_out, __ATOMIC_RELAXED, __HIP_MEMORY_SCOPE_AGENT) < t + Kv - RDv)
            __builtin_amdgcn_s_sleep(1);
        }
      }
      ctl_barrier();
      if (layer > 0) {
        const float* src = ring_in + (size_t)(t & RDm) * slot_sz;
        int i0 = tid * 4;
        if (i0 < NE) {
          u32x2 d = pack4(*(const f32x4*)(src + i0));
          *(u32x2*)&ibuf[par][i0 / HH][i0 % HH] = d;
        }
        int i1 = i0 + 1024;
        if (i1 < NE) {
          u32x2 d = pack4(*(const f32x4*)(src + i1));
          *(u32x2*)&ibuf[par][i1 / HH][i1 % HH] = d;
        }
      } else if (t == 0) {
        if (tid < BC) xin[0][tid] = x[(size_t)(chunk * BC + tid) * TTS];
      }
      lds_barrier();
    }

    // ---- issue deferred stores from step t-1 (stay in flight past barrier) ----
    if (have_ring_def) {
      float* dst = ring_out + (size_t)((t - 1) & RDm) * slot_sz;
      #pragma unroll
      for (int ntl = 0; ntl < 2; ++ntl)
        if (jcv[ntl] < HH)
          #pragma unroll
          for (int r = 0; r < 4; ++r)
            dst[(size_t)(quad * 4 + r) * HH + jcv[ntl]] = hreg[ntl][r];
      have_ring_def = false;
    }
    if (have_out_def) {
      if ((tid & 15) == 0)
        out[(size_t)(chunk * BC + (tid >> 4)) * TTS + (t - 1)] = dso;
      have_out_def = false;
    }

    // ---- prefetch inp_{t+1} into regs (staged into ibuf[nxt] post-compute) ----
    f32x4 p0 = {}, p1 = {};
    bool pre = false;
    if (layer > 0) {
      if (!batch_last && t + 1 < TTS) {
        const float* src = ring_in + (size_t)((t + 1) & RDm) * slot_sz;
        int i0 = tid * 4;
        if (i0 < NE) p0 = *(const f32x4*)(src + i0);
        if (i0 + 1024 < NE) p1 = *(const f32x4*)(src + i0 + 1024);
        pre = true;
      }
    } else {
      if (t + 1 < TTS && tid < BC) px = x[(size_t)(chunk * BC + tid) * TTS + (t + 1)];
    }

    // ---- MFMA: A = direct bf16 ds_read_b128, B 2-plane -> 2 MFMAs per kc ----
    f32x4 acc[2] = {}, acc2[2] = {};
    auto mfma_kc = [&](f32x4* accp, const unsigned short (*buf)[HSS], int koff, int bfi) {
      short8 A1 = *(const short8*)&buf[lp][koff + quad * 8];
      #pragma unroll
      for (int ntl = 0; ntl < 2; ++ntl) {
        accp[ntl] = __builtin_amdgcn_mfma_f32_16x16x32_bf16(
            A1, Bf[bfi][ntl][1], accp[ntl], 0, 0, 0);   // a1*b2 (small first)
        accp[ntl] = __builtin_amdgcn_mfma_f32_16x16x32_bf16(
            A1, Bf[bfi][ntl][0], accp[ntl], 0, 0, 0);   // a1*b1
      }
    };
    #pragma unroll
    for (int kc = 0; kc < 4; ++kc) mfma_kc(acc, hbuf[par], kc * 32, kc);
    if (layer > 0) {
      #pragma unroll
      for (int kc = 0; kc < 4; ++kc) mfma_kc(acc2, ibuf[par], kc * 32, kc + 4);
    }

    // ---- epilogue: merge, bias(+x*w0), tanh, pack bf16, write hbuf[nxt] ----
    #pragma unroll
    for (int ntl = 0; ntl < 2; ++ntl) {
      #pragma unroll
      for (int r = 0; r < 4; ++r) {
        const int m = quad * 4 + r;
        float v = acc[ntl][r] + acc2[ntl][r] + br[ntl];
        if (layer == 0) v += xin[par][m] * w0r[ntl];
        float h = fast_tanh(v);
        hreg[ntl][r] = h;
        if (jcv[ntl] < HH) hbuf[nxt][m][jcv[ntl]] = bf_rtn(h);
      }
    }

    // batch-last ring store cannot be deferred past the flag publish
    if (layer < NL - 1 && batch_last) {
      float* dst = ring_out + (size_t)(t & RDm) * slot_sz;
      #pragma unroll
      for (int ntl = 0; ntl < 2; ++ntl)
        if (jcv[ntl] < HH)
          #pragma unroll
          for (int r = 0; r < 4; ++r)
            dst[(size_t)(quad * 4 + r) * HH + jcv[ntl]] = hreg[ntl][r];
    }
    if (t == TTS - 1) {   // final hidden state, fp32-exact from registers
      #pragma unroll
      for (int ntl = 0; ntl < 2; ++ntl)
        if (jcv[ntl] < HH)
          #pragma unroll
          for (int r = 0; r < 4; ++r)
            out[(size_t)BBS * TTS +
                ((size_t)layer * BBS + chunk * BC + quad * 4 + r) * HH + jcv[ntl]] =
                hreg[ntl][r];
    }

    // ---- stage prefetched inp_{t+1} into ibuf[nxt] / xin[nxt] ----
    if (pre) {
      int i0 = tid * 4;
      if (i0 < NE) *(u32x2*)&ibuf[nxt][i0 / HH][i0 % HH] = pack4(p0);
      int i1 = i0 + 1024;
      if (i1 < NE) *(u32x2*)&ibuf[nxt][i1 / HH][i1 % HH] = pack4(p1);
    }
    if (layer == 0 && t + 1 < TTS && tid < BC) xin[nxt][tid] = px;

    if (batch_last) {
      __syncthreads();   // full drain: ALL waves' ring stores visible pre-flag
    } else {
      lds_barrier();     // LDS ordered; global stores remain in flight
    }

    // ---- flags (once per batch) ----
    if (batch_last && tid == 0) {
      if (layer < NL - 1)
        __hip_atomic_store(prog_out, t + 1, __ATOMIC_RELEASE, __HIP_MEMORY_SCOPE_AGENT);
      if (layer > 0)
        __hip_atomic_store(cons_in, t + 1, __ATOMIC_RELAXED, __HIP_MEMORY_SCOPE_AGENT);
    }

    // ---- layer-9 output dot (reads fresh hbuf[nxt], reconstruct bf16) ----
    if (layer == NL - 1) {
      const int b = tid >> 4, seg = tid & 15;
      float s = 0.f;
      #pragma unroll
      for (int jj = 0; jj < 7; ++jj) {
        const int j = seg * 7 + jj;
        if (j < HH) {
          float h = __uint_as_float((unsigned)hbuf[nxt][b][j] << 16);
          s += h * wouts[j];
        }
      }
      s += __shfl_xor(s, 1, 16);
      s += __shfl_xor(s, 2, 16);
      s += __shfl_xor(s, 4, 16);
      s += __shfl_xor(s, 8, 16);
      dso = s + boutv;
      if (t < TTS - 1) have_out_def = true;
    }
    if (layer < NL - 1 && !batch_last) have_ring_def = true;
  }

  // flush last layer-9 outputs (t = TTS-1)
  if (layer == NL - 1 && (tid & 15) == 0)
    out[(size_t)(chunk * BC + (tid >> 4)) * TTS + (TTS - 1)] = dso;
}

extern "C" void kernel_launch(void* const* d_in, const int* in_sizes, int n_in,
                              void* d_out, int out_size, void* d_ws, size_t ws_size,
                              hipStream_t stream) {
  const float* x    = (const float*)d_in[0];
  const float* h0   = (const float*)d_in[1];
  const float* Wih0 = (const float*)d_in[2];
  const float* Wih  = (const float*)d_in[3];
  const float* Whh  = (const float*)d_in[4];
  const float* bih  = (const float*)d_in[5];
  const float* bhh  = (const float*)d_in[6];
  const float* Wout = (const float*)d_in[7];
  const float* bout = (const float*)d_in[8];
  float* out = (float*)d_out;

  int*   wsi  = (int*)d_ws;
  float* ring = (float*)((char*)d_ws + 65536);

  // Pick deepest ring that fits ws: ring bytes = 9*32 * RD * 6400
  const size_t slot_bytes = (size_t)BC * HH * 4;   // 6400
  int RDv = 32;
  while (RDv > 2 && 65536 + (size_t)(NL - 1) * NB * RDv * slot_bytes > ws_size)
    RDv >>= 1;
  int Kv = RDv / 2;

  hipLaunchKernelGGL(init_ws_kernel, dim3(64), dim3(256), 0, stream, wsi);
  hipLaunchKernelGGL(rnn_pipe, dim3(NL * NB), dim3(NT), 0, stream,
                     x, h0, Wih0, Wih, Whh, bih, bhh, Wout, bout, out, ring, wsi,
                     Kv, RDv);
}